// Round 1
// baseline (971.040 us; speedup 1.0000x reference)
//
#include <hip/hip_runtime.h>
#include <stdint.h>

// Problem dims
constexpr int CB = 8;
constexpr int CS = 2048;
constexpr int CD = 1024;
constexpr int CH = 16;
constexpr int CDK = 64;
constexpr int CM = CB * CS; // 16384

typedef __attribute__((ext_vector_type(8))) short short8;
typedef __attribute__((ext_vector_type(4))) float f32x4;

__device__ __forceinline__ short f2bf(float f) {
  union { float f; uint32_t u; } v; v.f = f;
  uint32_t r = v.u + 0x7fffu + ((v.u >> 16) & 1u);
  return (short)(r >> 16);
}

// ---------------- weight transpose: W[H,D,DK] f32 -> Wt[H*DK][D] bf16 ----------------
__global__ __launch_bounds__(256) void wtrans_kernel(
    const float* __restrict__ Wq, const float* __restrict__ Wk,
    const float* __restrict__ Wv,
    short* __restrict__ Tq, short* __restrict__ Tk, short* __restrict__ Tv) {
  int blk = blockIdx.x;           // 3 * 16(h) * 16(dtile) = 768
  int which = blk >> 8;
  int rem = blk & 255;
  int h = rem >> 4;
  int dt = rem & 15;
  const float* W = (which == 0) ? Wq : ((which == 1) ? Wk : Wv);
  short* Wt = (which == 0) ? Tq : ((which == 1) ? Tk : Tv);
  __shared__ short T[64][65];
  int t = threadIdx.x;
  int i = t >> 2;                 // d-row within tile
  int kc = (t & 3) << 4;          // k-col start
  const float* src = W + ((size_t)h * CD + (size_t)(dt * 64 + i)) * CDK + kc;
#pragma unroll
  for (int u = 0; u < 16; u += 4) {
    float4 v = *(const float4*)(src + u);
    T[i][kc + u + 0] = f2bf(v.x);
    T[i][kc + u + 1] = f2bf(v.y);
    T[i][kc + u + 2] = f2bf(v.z);
    T[i][kc + u + 3] = f2bf(v.w);
  }
  __syncthreads();
  int kk = t >> 2;                // output k-row
  int dc = (t & 3) << 4;          // output d-col start
  short* dst = Wt + (size_t)(h * 64 + kk) * CD + dt * 64 + dc;
  short8 o0, o1;
#pragma unroll
  for (int u = 0; u < 8; ++u) o0[u] = T[dc + u][kk];
#pragma unroll
  for (int u = 0; u < 8; ++u) o1[u] = T[dc + 8 + u][kk];
  *(short8*)dst = o0;
  *(short8*)(dst + 8) = o1;
}

// ---------------- Wo: straight f32 -> bf16 copy ([n][d] is already B^T) ----------------
__global__ __launch_bounds__(256) void woconv_kernel(const float* __restrict__ Wo,
                                                     short* __restrict__ To) {
  size_t idx = ((size_t)blockIdx.x * 256 + threadIdx.x) * 8;
  float4 a = *(const float4*)(Wo + idx);
  float4 b = *(const float4*)(Wo + idx + 4);
  short8 o;
  o[0] = f2bf(a.x); o[1] = f2bf(a.y); o[2] = f2bf(a.z); o[3] = f2bf(a.w);
  o[4] = f2bf(b.x); o[5] = f2bf(b.y); o[6] = f2bf(b.z); o[7] = f2bf(b.w);
  *(short8*)(To + idx) = o;
}

// ---------------- GEMM: C[M,N] = A[M,K] * Bt[N,K]^T, bf16 MFMA ----------------
// BM=BN=128, BK=32; 4 waves, each 64x64 (4x4 frags of 16x16x32)
template <bool A_F32, bool B_F32, bool C_BF16>
__global__ __launch_bounds__(256) void gemm_kernel(
    const void* __restrict__ Ap, const void* __restrict__ Bp,
    void* __restrict__ Cp, int M, int N, int K, float scale) {
  __shared__ __align__(16) short Ash[128 * 32];
  __shared__ __align__(16) short Bsh[128 * 32];
  const int m0 = blockIdx.x * 128, n0 = blockIdx.y * 128;
  const int tid = threadIdx.x;
  const int lane = tid & 63, w = tid >> 6;
  const int wr = w >> 1, wc = w & 1;
  const int lm = lane & 15, lg = lane >> 4;
  const int srow = tid >> 1, shalf = tid & 1;

  f32x4 acc[4][4];
#pragma unroll
  for (int i = 0; i < 4; ++i)
#pragma unroll
    for (int j = 0; j < 4; ++j) acc[i][j] = (f32x4)0.0f;

  for (int k0 = 0; k0 < K; k0 += 32) {
    // ---- stage A tile (rows m0+srow, cols k0 + shalf*16 .. +15)
    if (A_F32) {
      const float* A = (const float*)Ap;
      const float* src = A + (size_t)(m0 + srow) * K + k0 + shalf * 16;
      float4 f0 = *(const float4*)(src + 0);
      float4 f1 = *(const float4*)(src + 4);
      float4 f2 = *(const float4*)(src + 8);
      float4 f3 = *(const float4*)(src + 12);
      short8 v0, v1;
      v0[0] = f2bf(f0.x); v0[1] = f2bf(f0.y); v0[2] = f2bf(f0.z); v0[3] = f2bf(f0.w);
      v0[4] = f2bf(f1.x); v0[5] = f2bf(f1.y); v0[6] = f2bf(f1.z); v0[7] = f2bf(f1.w);
      v1[0] = f2bf(f2.x); v1[1] = f2bf(f2.y); v1[2] = f2bf(f2.z); v1[3] = f2bf(f2.w);
      v1[4] = f2bf(f3.x); v1[5] = f2bf(f3.y); v1[6] = f2bf(f3.z); v1[7] = f2bf(f3.w);
      *(short8*)&Ash[srow * 32 + shalf * 16] = v0;
      *(short8*)&Ash[srow * 32 + shalf * 16 + 8] = v1;
    } else {
      const short* A = (const short*)Ap;
      const short* src = A + (size_t)(m0 + srow) * K + k0 + shalf * 16;
      *(short8*)&Ash[srow * 32 + shalf * 16] = *(const short8*)src;
      *(short8*)&Ash[srow * 32 + shalf * 16 + 8] = *(const short8*)(src + 8);
    }
    // ---- stage B^T tile (rows n0+srow, cols k0 + shalf*16 .. +15)
    if (B_F32) {
      const float* Bm = (const float*)Bp;
      const float* src = Bm + (size_t)(n0 + srow) * K + k0 + shalf * 16;
      float4 f0 = *(const float4*)(src + 0);
      float4 f1 = *(const float4*)(src + 4);
      float4 f2 = *(const float4*)(src + 8);
      float4 f3 = *(const float4*)(src + 12);
      short8 v0, v1;
      v0[0] = f2bf(f0.x); v0[1] = f2bf(f0.y); v0[2] = f2bf(f0.z); v0[3] = f2bf(f0.w);
      v0[4] = f2bf(f1.x); v0[5] = f2bf(f1.y); v0[6] = f2bf(f1.z); v0[7] = f2bf(f1.w);
      v1[0] = f2bf(f2.x); v1[1] = f2bf(f2.y); v1[2] = f2bf(f2.z); v1[3] = f2bf(f2.w);
      v1[4] = f2bf(f3.x); v1[5] = f2bf(f3.y); v1[6] = f2bf(f3.z); v1[7] = f2bf(f3.w);
      *(short8*)&Bsh[srow * 32 + shalf * 16] = v0;
      *(short8*)&Bsh[srow * 32 + shalf * 16 + 8] = v1;
    } else {
      const short* Bm = (const short*)Bp;
      const short* src = Bm + (size_t)(n0 + srow) * K + k0 + shalf * 16;
      *(short8*)&Bsh[srow * 32 + shalf * 16] = *(const short8*)src;
      *(short8*)&Bsh[srow * 32 + shalf * 16 + 8] = *(const short8*)(src + 8);
    }
    __syncthreads();
    short8 a[4], b[4];
#pragma unroll
    for (int mf = 0; mf < 4; ++mf)
      a[mf] = *(const short8*)&Ash[(wr * 64 + mf * 16 + lm) * 32 + lg * 8];
#pragma unroll
    for (int nf = 0; nf < 4; ++nf)
      b[nf] = *(const short8*)&Bsh[(wc * 64 + nf * 16 + lm) * 32 + lg * 8];
#pragma unroll
    for (int mf = 0; mf < 4; ++mf)
#pragma unroll
      for (int nf = 0; nf < 4; ++nf)
        acc[mf][nf] = __builtin_amdgcn_mfma_f32_16x16x32_bf16(a[mf], b[nf], acc[mf][nf], 0, 0, 0);
    __syncthreads();
  }
  // ---- epilogue: C row = m0+wr*64+mf*16+lg*4+r, col = n0+wc*64+nf*16+lm
#pragma unroll
  for (int mf = 0; mf < 4; ++mf)
#pragma unroll
    for (int nf = 0; nf < 4; ++nf)
#pragma unroll
      for (int r = 0; r < 4; ++r) {
        int row = m0 + wr * 64 + mf * 16 + lg * 4 + r;
        int col = n0 + wc * 64 + nf * 16 + lm;
        float v = acc[mf][nf][r] * scale;
        if (C_BF16) ((short*)Cp)[(size_t)row * N + col] = f2bf(v);
        else        ((float*)Cp)[(size_t)row * N + col] = v;
      }
}

// ---------------- flash attention ----------------
// grid (S/128, B*H); 256 threads = 4 waves, each wave 32 q-rows; KV tile 64
// Qp/Kp: [B,S,H*DK] bf16 (Qp pre-scaled by 1/32); Vt: [H*DK, B*S] bf16
__global__ __launch_bounds__(256) void attn_kernel(
    const short* __restrict__ Qp, const short* __restrict__ Kp,
    const short* __restrict__ Vt, short* __restrict__ Out) {
  const int qt = blockIdx.x;
  const int bh = blockIdx.y;
  const int b = bh >> 4, h = bh & 15;
  const int tid = threadIdx.x;
  const int lane = tid & 63, w = tid >> 6;
  const int lm = lane & 15, lg = lane >> 4;

  __shared__ __align__(16) short Ksh[64 * 72];
  __shared__ __align__(16) short Vsh[64 * 72];
  __shared__ __align__(16) short Psh[4][32 * 72];

  const size_t qk_head = ((size_t)b * CS * CH + h) * CDK;           // + s*1024 + k
  const size_t vt_head = (size_t)(h * CDK) * CM + (size_t)b * CS;   // + dk*16384 + t

  const int q0 = qt * 128 + w * 32;
  short8 qf[2][2];
#pragma unroll
  for (int mf = 0; mf < 2; ++mf)
#pragma unroll
    for (int ks = 0; ks < 2; ++ks)
      qf[mf][ks] = *(const short8*)(Qp + qk_head +
                     (size_t)(q0 + mf * 16 + lm) * (CH * CDK) + ks * 32 + lg * 8);

  f32x4 oacc[2][4];
  float mrun[2][4], lrun[2][4];
#pragma unroll
  for (int mf = 0; mf < 2; ++mf) {
#pragma unroll
    for (int nf = 0; nf < 4; ++nf) oacc[mf][nf] = (f32x4)0.0f;
#pragma unroll
    for (int r = 0; r < 4; ++r) { mrun[mf][r] = -1e30f; lrun[mf][r] = 0.0f; }
  }

  const int str = tid >> 3;        // staging row 0..31
  const int stc = (tid & 7) * 8;   // staging col

  for (int t0 = 0; t0 < CS; t0 += 64) {
    __syncthreads();
#pragma unroll
    for (int i = 0; i < 2; ++i) {
      int rr = str + i * 32;
      *(short8*)&Ksh[rr * 72 + stc] =
          *(const short8*)(Kp + qk_head + (size_t)(t0 + rr) * (CH * CDK) + stc);
      *(short8*)&Vsh[rr * 72 + stc] =
          *(const short8*)(Vt + vt_head + (size_t)rr * CM + t0 + stc);
    }
    __syncthreads();
    // QK^T
    f32x4 sc4[2][4];
#pragma unroll
    for (int mf = 0; mf < 2; ++mf)
#pragma unroll
      for (int nf = 0; nf < 4; ++nf) sc4[mf][nf] = (f32x4)0.0f;
    short8 kf[4][2];
#pragma unroll
    for (int nf = 0; nf < 4; ++nf)
#pragma unroll
      for (int ks = 0; ks < 2; ++ks)
        kf[nf][ks] = *(const short8*)&Ksh[(nf * 16 + lm) * 72 + ks * 32 + lg * 8];
#pragma unroll
    for (int mf = 0; mf < 2; ++mf)
#pragma unroll
      for (int nf = 0; nf < 4; ++nf) {
        sc4[mf][nf] = __builtin_amdgcn_mfma_f32_16x16x32_bf16(qf[mf][0], kf[nf][0], sc4[mf][nf], 0, 0, 0);
        sc4[mf][nf] = __builtin_amdgcn_mfma_f32_16x16x32_bf16(qf[mf][1], kf[nf][1], sc4[mf][nf], 0, 0, 0);
      }
    // online softmax; row = mf*16 + lg*4 + r, cols in 16-lane group
#pragma unroll
    for (int mf = 0; mf < 2; ++mf)
#pragma unroll
      for (int r = 0; r < 4; ++r) {
        float tm = fmaxf(fmaxf(sc4[mf][0][r], sc4[mf][1][r]),
                         fmaxf(sc4[mf][2][r], sc4[mf][3][r]));
        tm = fmaxf(tm, __shfl_xor(tm, 1));
        tm = fmaxf(tm, __shfl_xor(tm, 2));
        tm = fmaxf(tm, __shfl_xor(tm, 4));
        tm = fmaxf(tm, __shfl_xor(tm, 8));
        float mnew = fmaxf(mrun[mf][r], tm);
        float alpha = __expf(mrun[mf][r] - mnew);
        mrun[mf][r] = mnew;
        float rs = 0.0f;
#pragma unroll
        for (int nf = 0; nf < 4; ++nf) {
          float p = __expf(sc4[mf][nf][r] - mnew);
          sc4[mf][nf][r] = p;
          rs += p;
        }
        rs += __shfl_xor(rs, 1);
        rs += __shfl_xor(rs, 2);
        rs += __shfl_xor(rs, 4);
        rs += __shfl_xor(rs, 8);
        lrun[mf][r] = lrun[mf][r] * alpha + rs;
#pragma unroll
        for (int nf = 0; nf < 4; ++nf) oacc[mf][nf][r] *= alpha;
      }
    // write P (bf16) to per-wave LDS
#pragma unroll
    for (int mf = 0; mf < 2; ++mf)
#pragma unroll
      for (int nf = 0; nf < 4; ++nf)
#pragma unroll
        for (int r = 0; r < 4; ++r)
          Psh[w][(mf * 16 + lg * 4 + r) * 72 + nf * 16 + lm] = f2bf(sc4[mf][nf][r]);
    __syncthreads();
    // PV
    short8 pf[2][2], vf[4][2];
#pragma unroll
    for (int mf = 0; mf < 2; ++mf)
#pragma unroll
      for (int ks = 0; ks < 2; ++ks)
        pf[mf][ks] = *(const short8*)&Psh[w][(mf * 16 + lm) * 72 + ks * 32 + lg * 8];
#pragma unroll
    for (int nf = 0; nf < 4; ++nf)
#pragma unroll
      for (int ks = 0; ks < 2; ++ks)
        vf[nf][ks] = *(const short8*)&Vsh[(nf * 16 + lm) * 72 + ks * 32 + lg * 8];
#pragma unroll
    for (int mf = 0; mf < 2; ++mf)
#pragma unroll
      for (int nf = 0; nf < 4; ++nf) {
        oacc[mf][nf] = __builtin_amdgcn_mfma_f32_16x16x32_bf16(pf[mf][0], vf[nf][0], oacc[mf][nf], 0, 0, 0);
        oacc[mf][nf] = __builtin_amdgcn_mfma_f32_16x16x32_bf16(pf[mf][1], vf[nf][1], oacc[mf][nf], 0, 0, 0);
      }
  }
  // epilogue: Out[b, s, h*64 + n] bf16
#pragma unroll
  for (int mf = 0; mf < 2; ++mf)
#pragma unroll
    for (int r = 0; r < 4; ++r) {
      int srow = q0 + mf * 16 + lg * 4 + r;
      float inv = 1.0f / lrun[mf][r];
#pragma unroll
      for (int nf = 0; nf < 4; ++nf)
        Out[(size_t)(b * CS + srow) * CD + h * CDK + nf * 16 + lm] =
            f2bf(oacc[mf][nf][r] * inv);
    }
}

extern "C" void kernel_launch(void* const* d_in, const int* in_sizes, int n_in,
                              void* d_out, int out_size, void* d_ws, size_t ws_size,
                              hipStream_t stream) {
  const float* query = (const float*)d_in[0];
  const float* key   = (const float*)d_in[1];
  const float* value = (const float*)d_in[2];
  const float* Wq    = (const float*)d_in[3];
  const float* Wk    = (const float*)d_in[4];
  const float* Wv    = (const float*)d_in[5];
  const float* Wo    = (const float*)d_in[6];
  float* out = (float*)d_out;
  char* ws = (char*)d_ws;

  const size_t MB = 1u << 20;
  short* Tq = (short*)(ws + 0 * MB);    // [1024,1024] bf16 = 2MB
  short* Tk = (short*)(ws + 2 * MB);
  short* Tv = (short*)(ws + 4 * MB);
  short* To = (short*)(ws + 6 * MB);
  short* Qp = (short*)(ws + 8 * MB);    // [16384,1024] bf16 = 32MB (pre-scaled 1/32)
  short* Kp = (short*)(ws + 40 * MB);   // [16384,1024] bf16
  short* Vtg = (short*)(ws + 72 * MB);  // [1024,16384] bf16 (V^T)
  short* AO = (short*)(ws + 104 * MB);  // [16384,1024] bf16 — total 136MB

  wtrans_kernel<<<dim3(768), dim3(256), 0, stream>>>(Wq, Wk, Wv, Tq, Tk, Tv);
  woconv_kernel<<<dim3(512), dim3(256), 0, stream>>>(Wo, To);

  // q = X @ Wq' (scaled by d_model^-0.5), k = X @ Wk'
  gemm_kernel<true, false, true><<<dim3(128, 8), dim3(256), 0, stream>>>(
      query, Tq, Qp, CM, CD, CD, 0.03125f);
  gemm_kernel<true, false, true><<<dim3(128, 8), dim3(256), 0, stream>>>(
      key, Tk, Kp, CM, CD, CD, 1.0f);
  // V^T = Wv' @ X^T  (A = Tv [1024,1024] bf16, Bt = value [16384,1024] f32)
  gemm_kernel<false, true, true><<<dim3(8, 128), dim3(256), 0, stream>>>(
      Tv, value, Vtg, CD, CM, CD, 1.0f);

  attn_kernel<<<dim3(16, 128), dim3(256), 0, stream>>>(Qp, Kp, Vtg, AO);

  // out = AO @ Wo^T (fp32 out)
  gemm_kernel<false, false, false><<<dim3(128, 8), dim3(256), 0, stream>>>(
      AO, To, out, CM, CD, CD, 1.0f);
}

// Round 2
// 657.481 us; speedup vs baseline: 1.4769x; 1.4769x over previous
//
#include <hip/hip_runtime.h>
#include <hip/hip_bf16.h>
#include <stdint.h>

// Problem dims
constexpr int CB = 8;
constexpr int CS = 2048;
constexpr int CD = 1024;
constexpr int CH = 16;
constexpr int CDK = 64;
constexpr int CM = CB * CS; // 16384

typedef __attribute__((ext_vector_type(8))) short short8;
typedef __attribute__((ext_vector_type(4))) float f32x4;
typedef __attribute__((ext_vector_type(16))) float f32x16;

__device__ __forceinline__ short f2bf(float f) {
  union { float f; uint32_t u; } v; v.f = f;
  uint32_t r = v.u + 0x7fffu + ((v.u >> 16) & 1u);
  return (short)(r >> 16);
}

// pack two f32 -> one u32 of 2 bf16 (RNE); compiler can fuse to v_cvt_pk_bf16_f32
__device__ __forceinline__ uint32_t pk2(float lo, float hi) {
  union { __hip_bfloat16 h; unsigned short u; } a, b;
  a.h = __float2bfloat16(lo); b.h = __float2bfloat16(hi);
  return (uint32_t)a.u | ((uint32_t)b.u << 16);
}

// v_permlane32_swap: a' = [a.lo32 | b.lo32], b' = [a.hi32 | b.hi32]
__device__ __forceinline__ void plswap(uint32_t& a, uint32_t& b) {
#if __has_builtin(__builtin_amdgcn_permlane32_swap)
  auto r = __builtin_amdgcn_permlane32_swap((int)a, (int)b, false, false);
  a = (uint32_t)r[0]; b = (uint32_t)r[1];
#else
  uint32_t sa = (uint32_t)__shfl_xor((int)a, 32);
  uint32_t sb = (uint32_t)__shfl_xor((int)b, 32);
  uint32_t na = (threadIdx.x & 32) ? sb : a;
  uint32_t nb = (threadIdx.x & 32) ? b : sa;
  a = na; b = nb;
#endif
}

__device__ __forceinline__ float fexp2(float x) {
#if __has_builtin(__builtin_amdgcn_exp2f)
  return __builtin_amdgcn_exp2f(x);
#else
  return exp2f(x);
#endif
}

// async global->LDS, 16B per lane; per-lane lds ptr must equal wave-base + lane*16
__device__ __forceinline__ void gload_lds16(const void* g, void* l) {
#if __has_builtin(__builtin_amdgcn_global_load_lds)
  typedef __attribute__((address_space(1))) unsigned int as1_u32;
  typedef __attribute__((address_space(3))) unsigned int as3_u32;
  __builtin_amdgcn_global_load_lds((as1_u32*)g, (as3_u32*)l, 16, 0, 0);
#else
  *(short8*)l = *(const short8*)g;
#endif
}

// ---------------- f32 -> bf16 bulk convert ----------------
__global__ __launch_bounds__(256) void cvt_kernel(const float* __restrict__ in,
                                                  short* __restrict__ out, int n8) {
  int stride = gridDim.x * 256;
  for (int i = blockIdx.x * 256 + threadIdx.x; i < n8; i += stride) {
    const float4* p = (const float4*)(in + (size_t)i * 8);
    float4 a = p[0], b = p[1];
    short8 o;
    o[0] = f2bf(a.x); o[1] = f2bf(a.y); o[2] = f2bf(a.z); o[3] = f2bf(a.w);
    o[4] = f2bf(b.x); o[5] = f2bf(b.y); o[6] = f2bf(b.z); o[7] = f2bf(b.w);
    *(short8*)(out + (size_t)i * 8) = o;
  }
}

// ---------------- weight transpose: W[H,D,DK] f32 -> Wt[H*DK][D] bf16 ----------------
__global__ __launch_bounds__(256) void wtrans_kernel(
    const float* __restrict__ Wq, const float* __restrict__ Wk,
    const float* __restrict__ Wv,
    short* __restrict__ Tq, short* __restrict__ Tk, short* __restrict__ Tv) {
  int blk = blockIdx.x;           // 3 * 16(h) * 16(dtile) = 768
  int which = blk >> 8;
  int rem = blk & 255;
  int h = rem >> 4;
  int dt = rem & 15;
  const float* W = (which == 0) ? Wq : ((which == 1) ? Wk : Wv);
  short* Wt = (which == 0) ? Tq : ((which == 1) ? Tk : Tv);
  __shared__ short T[64][65];
  int t = threadIdx.x;
  int i = t >> 2;
  int kc = (t & 3) << 4;
  const float* src = W + ((size_t)h * CD + (size_t)(dt * 64 + i)) * CDK + kc;
#pragma unroll
  for (int u = 0; u < 16; u += 4) {
    float4 v = *(const float4*)(src + u);
    T[i][kc + u + 0] = f2bf(v.x);
    T[i][kc + u + 1] = f2bf(v.y);
    T[i][kc + u + 2] = f2bf(v.z);
    T[i][kc + u + 3] = f2bf(v.w);
  }
  __syncthreads();
  int kk = t >> 2;
  int dc = (t & 3) << 4;
  short* dst = Wt + (size_t)(h * 64 + kk) * CD + dt * 64 + dc;
  short8 o0, o1;
#pragma unroll
  for (int u = 0; u < 8; ++u) o0[u] = T[dc + u][kk];
#pragma unroll
  for (int u = 0; u < 8; ++u) o1[u] = T[dc + 8 + u][kk];
  *(short8*)dst = o0;
  *(short8*)(dst + 8) = o1;
}

// ---------------- Wo: f32 -> bf16 ([n][d] is already B^T) ----------------
__global__ __launch_bounds__(256) void woconv_kernel(const float* __restrict__ Wo,
                                                     short* __restrict__ To) {
  size_t idx = ((size_t)blockIdx.x * 256 + threadIdx.x) * 8;
  float4 a = *(const float4*)(Wo + idx);
  float4 b = *(const float4*)(Wo + idx + 4);
  short8 o;
  o[0] = f2bf(a.x); o[1] = f2bf(a.y); o[2] = f2bf(a.z); o[3] = f2bf(a.w);
  o[4] = f2bf(b.x); o[5] = f2bf(b.y); o[6] = f2bf(b.z); o[7] = f2bf(b.w);
  *(short8*)(To + idx) = o;
}

// ---------------- GEMM (m97 structure): C[M,N] = A[M,K] * Bt[N,K]^T ----------------
// BM=BN=128, BK=32; 4 waves, 4x4 frags of 16x16x32; global_load_lds width-16 staging
template <bool C_BF16>
__global__ __launch_bounds__(256) void gemm16_kernel(
    const short* __restrict__ A, const short* __restrict__ Bt,
    void* __restrict__ Cp, int M, int N, int K, float scale) {
  __shared__ __align__(16) short Ash[128 * 32];
  __shared__ __align__(16) short Bsh[128 * 32];
  const int m0 = blockIdx.x * 128, n0 = blockIdx.y * 128;
  const int tid = threadIdx.x;
  const int lane = tid & 63, w = tid >> 6;
  const int wr = w >> 1, wc = w & 1;
  const int lm = lane & 15, lg = lane >> 4;

  f32x4 acc[4][4];
#pragma unroll
  for (int i = 0; i < 4; ++i)
#pragma unroll
    for (int j = 0; j < 4; ++j) acc[i][j] = (f32x4)0.0f;

  for (int k0 = 0; k0 < K; k0 += 32) {
#pragma unroll
    for (int r = 0; r < 2; ++r) {
      int idx = r * 256 + tid;
      int row = idx >> 2;              // 4 chunks of 16B per 64B row
      int ce = (idx & 3) * 8;          // element col
      gload_lds16(A + (size_t)(m0 + row) * K + k0 + ce, (char*)Ash + idx * 16);
      gload_lds16(Bt + (size_t)(n0 + row) * K + k0 + ce, (char*)Bsh + idx * 16);
    }
    __syncthreads();                   // drains vmcnt -> tiles ready
    short8 a[4], b[4];
#pragma unroll
    for (int mf = 0; mf < 4; ++mf)
      a[mf] = *(const short8*)&Ash[(wr * 64 + mf * 16 + lm) * 32 + lg * 8];
#pragma unroll
    for (int nf = 0; nf < 4; ++nf)
      b[nf] = *(const short8*)&Bsh[(wc * 64 + nf * 16 + lm) * 32 + lg * 8];
#pragma unroll
    for (int mf = 0; mf < 4; ++mf)
#pragma unroll
      for (int nf = 0; nf < 4; ++nf)
        acc[mf][nf] = __builtin_amdgcn_mfma_f32_16x16x32_bf16(a[mf], b[nf], acc[mf][nf], 0, 0, 0);
    __syncthreads();
  }
#pragma unroll
  for (int mf = 0; mf < 4; ++mf)
#pragma unroll
    for (int nf = 0; nf < 4; ++nf)
#pragma unroll
      for (int r = 0; r < 4; ++r) {
        int row = m0 + wr * 64 + mf * 16 + lg * 4 + r;
        int col = n0 + wc * 64 + nf * 16 + lm;
        float v = acc[mf][nf][r] * scale;
        if (C_BF16) ((short*)Cp)[(size_t)row * N + col] = f2bf(v);
        else        ((float*)Cp)[(size_t)row * N + col] = v;
      }
}

// ---------------- flash attention, swapped-operand 32x32, in-register softmax ----------
// grid (S/128, B*H); 256 threads = 4 waves, each wave 32 q-rows; KV tile 64.
// Qp/Kp: [B,S,H*DK] bf16 (Qp pre-scaled by log2e/32); Vt: [H*DK, B*S] bf16.
// Per lane: q = lane&31. S^T = mfma(A=K, B=Q): lane holds S[q][kt], kt=(reg&3)+8(reg>>2)+4hi (+32 for frag 1).
// O^T = mfma(A=V^T, B=P): lane holds O[q][d], d same reg pattern. All state q-lane-local.
__global__ __launch_bounds__(256, 2) void attn_kernel(
    const short* __restrict__ Qp, const short* __restrict__ Kp,
    const short* __restrict__ Vt, short* __restrict__ Out) {
  __shared__ __align__(16) short Ksh[2][4096];  // [64 kt][64 d] XOR-swizzled, x2 buf
  __shared__ __align__(16) short Vsh[2][4096];  // [64 d][64 t]  XOR-swizzled, x2 buf
  const int qt = blockIdx.x, bh = blockIdx.y;
  const int b = bh >> 4, h = bh & 15;
  const int tid = threadIdx.x;
  const int lane = tid & 63, w = tid >> 6;
  const int l31 = lane & 31, hi = lane >> 5;
  const int swz = (lane & 7) << 4;   // row&7 == lane&7 for both 32-row halves

  const size_t qk_head = ((size_t)b * CS * CH + h) * CDK;
  const size_t vt_head = (size_t)(h * CDK) * CM + (size_t)b * CS;
  const int q0 = qt * 128 + w * 32;

  // Q fragments: B[col=q=l31][k = ds*16 + 8*hi + e]
  short8 qf[4];
#pragma unroll
  for (int ds = 0; ds < 4; ++ds)
    qf[ds] = *(const short8*)(Qp + qk_head + (size_t)(q0 + l31) * CD + ds * 16 + 8 * hi);

  f32x16 oT0 = (f32x16)0.0f, oT1 = (f32x16)0.0f;
  float mrun = -1e30f, lrun = 0.0f;

  const short* Kg0 = Kp + qk_head;
  const short* Vg0 = Vt + vt_head;

  // prologue: stage tile 0 into buf 0 (pre-swizzled global source, linear LDS dest)
#pragma unroll
  for (int r = 0; r < 2; ++r) {
    int idx = r * 256 + tid;
    int row = idx >> 3;
    int cb = ((idx & 7) * 16) ^ ((row & 7) << 4);   // logical byte col for this lds slot
    gload_lds16(Kg0 + (size_t)row * CD + (cb >> 1), (char*)&Ksh[0][0] + idx * 16);
    gload_lds16(Vg0 + (size_t)row * CM + (cb >> 1), (char*)&Vsh[0][0] + idx * 16);
  }

  int cur = 0;
  for (int it = 0; it < CS / 64; ++it) {
    __syncthreads();   // drains vmcnt: buf[cur] ready; all prev reads of buf[cur^1] done
    if (it + 1 < CS / 64) {
      const short* Kg = Kg0 + (size_t)(it + 1) * 64 * CD;
      const short* Vg = Vg0 + (size_t)(it + 1) * 64;
#pragma unroll
      for (int r = 0; r < 2; ++r) {
        int idx = r * 256 + tid;
        int row = idx >> 3;
        int cb = ((idx & 7) * 16) ^ ((row & 7) << 4);
        gload_lds16(Kg + (size_t)row * CD + (cb >> 1), (char*)&Ksh[cur ^ 1][0] + idx * 16);
        gload_lds16(Vg + (size_t)row * CM + (cb >> 1), (char*)&Vsh[cur ^ 1][0] + idx * 16);
      }
    }
    const char* Kb = (const char*)&Ksh[cur][0];
    const char* Vb = (const char*)&Vsh[cur][0];

    // QK^T (swapped): S^T[kt][q]
    f32x16 sc0 = (f32x16)0.0f, sc1 = (f32x16)0.0f;
#pragma unroll
    for (int ds = 0; ds < 4; ++ds) {
      int csw = (ds * 32 + 16 * hi) ^ swz;
      short8 k0v = *(const short8*)(Kb + l31 * 128 + csw);
      short8 k1v = *(const short8*)(Kb + (l31 + 32) * 128 + csw);
      sc0 = __builtin_amdgcn_mfma_f32_32x32x16_bf16(k0v, qf[ds], sc0, 0, 0, 0);
      sc1 = __builtin_amdgcn_mfma_f32_32x32x16_bf16(k1v, qf[ds], sc1, 0, 0, 0);
    }

    // online softmax (base-2 domain), fully lane-local for q = l31
    float a0 = fmaxf(fmaxf(sc0[0], sc0[1]), fmaxf(sc0[2], sc0[3]));
    float a1 = fmaxf(fmaxf(sc0[4], sc0[5]), fmaxf(sc0[6], sc0[7]));
    float a2 = fmaxf(fmaxf(sc0[8], sc0[9]), fmaxf(sc0[10], sc0[11]));
    float a3 = fmaxf(fmaxf(sc0[12], sc0[13]), fmaxf(sc0[14], sc0[15]));
    float a4 = fmaxf(fmaxf(sc1[0], sc1[1]), fmaxf(sc1[2], sc1[3]));
    float a5 = fmaxf(fmaxf(sc1[4], sc1[5]), fmaxf(sc1[6], sc1[7]));
    float a6 = fmaxf(fmaxf(sc1[8], sc1[9]), fmaxf(sc1[10], sc1[11]));
    float a7 = fmaxf(fmaxf(sc1[12], sc1[13]), fmaxf(sc1[14], sc1[15]));
    float tm = fmaxf(fmaxf(fmaxf(a0, a1), fmaxf(a2, a3)),
                     fmaxf(fmaxf(a4, a5), fmaxf(a6, a7)));
    tm = fmaxf(tm, __shfl_xor(tm, 32));
    float mnew = fmaxf(mrun, tm);
    float alpha = fexp2(mrun - mnew);
    mrun = mnew;
    float s0 = 0.f, s1 = 0.f, s2 = 0.f, s3 = 0.f;
#pragma unroll
    for (int i = 0; i < 16; i += 4) {
      sc0[i]     = fexp2(sc0[i]     - mnew); s0 += sc0[i];
      sc0[i + 1] = fexp2(sc0[i + 1] - mnew); s1 += sc0[i + 1];
      sc0[i + 2] = fexp2(sc0[i + 2] - mnew); s2 += sc0[i + 2];
      sc0[i + 3] = fexp2(sc0[i + 3] - mnew); s3 += sc0[i + 3];
    }
#pragma unroll
    for (int i = 0; i < 16; i += 4) {
      sc1[i]     = fexp2(sc1[i]     - mnew); s0 += sc1[i];
      sc1[i + 1] = fexp2(sc1[i + 1] - mnew); s1 += sc1[i + 1];
      sc1[i + 2] = fexp2(sc1[i + 2] - mnew); s2 += sc1[i + 2];
      sc1[i + 3] = fexp2(sc1[i + 3] - mnew); s3 += sc1[i + 3];
    }
    float rs = (s0 + s1) + (s2 + s3);
    rs += __shfl_xor(rs, 32);
    lrun = lrun * alpha + rs;
#pragma unroll
    for (int i = 0; i < 16; ++i) { oT0[i] *= alpha; oT1[i] *= alpha; }

    // pack P -> PV B-fragments via cvt_pk + permlane32_swap
    short8 pw[4];
#pragma unroll
    for (int ks = 0; ks < 4; ++ks) {
      const f32x16& P = (ks < 2) ? sc0 : sc1;
      const int r0 = (ks & 1) * 8;
      uint32_t A0 = pk2(P[r0 + 0], P[r0 + 1]);
      uint32_t B0 = pk2(P[r0 + 4], P[r0 + 5]);
      uint32_t A1 = pk2(P[r0 + 2], P[r0 + 3]);
      uint32_t B1 = pk2(P[r0 + 6], P[r0 + 7]);
      plswap(A0, B0);   // -> word0, word2
      plswap(A1, B1);   // -> word1, word3
      union { uint32_t u[4]; short8 s; } cv;
      cv.u[0] = A0; cv.u[1] = A1; cv.u[2] = B0; cv.u[3] = B1;
      pw[ks] = cv.s;
    }

    // PV^T: O^T[d][q] += V^T[d][t] * P[q][t]
#pragma unroll
    for (int ks = 0; ks < 4; ++ks) {
      int csw = (ks * 32 + 16 * hi) ^ swz;
      short8 v0 = *(const short8*)(Vb + l31 * 128 + csw);
      short8 v1 = *(const short8*)(Vb + (l31 + 32) * 128 + csw);
      oT0 = __builtin_amdgcn_mfma_f32_32x32x16_bf16(v0, pw[ks], oT0, 0, 0, 0);
      oT1 = __builtin_amdgcn_mfma_f32_32x32x16_bf16(v1, pw[ks], oT1, 0, 0, 0);
    }
    cur ^= 1;
  }

  // epilogue: lane q = l31; d = va*32 + 8*j + 4*hi + (0..3)
  float inv = 1.0f / lrun;
  short* Ob = Out + ((size_t)b * CS + q0 + l31) * CD + h * CDK;
#pragma unroll
  for (int j = 0; j < 4; ++j) {
    short4 o0, o1;
    o0.x = f2bf(oT0[4 * j + 0] * inv);
    o0.y = f2bf(oT0[4 * j + 1] * inv);
    o0.z = f2bf(oT0[4 * j + 2] * inv);
    o0.w = f2bf(oT0[4 * j + 3] * inv);
    *(short4*)(Ob + 8 * j + 4 * hi) = o0;
    o1.x = f2bf(oT1[4 * j + 0] * inv);
    o1.y = f2bf(oT1[4 * j + 1] * inv);
    o1.z = f2bf(oT1[4 * j + 2] * inv);
    o1.w = f2bf(oT1[4 * j + 3] * inv);
    *(short4*)(Ob + 32 + 8 * j + 4 * hi) = o1;
  }
}

extern "C" void kernel_launch(void* const* d_in, const int* in_sizes, int n_in,
                              void* d_out, int out_size, void* d_ws, size_t ws_size,
                              hipStream_t stream) {
  const float* query = (const float*)d_in[0];
  const float* key   = (const float*)d_in[1];
  const float* value = (const float*)d_in[2];
  const float* Wq    = (const float*)d_in[3];
  const float* Wk    = (const float*)d_in[4];
  const float* Wv    = (const float*)d_in[5];
  const float* Wo    = (const float*)d_in[6];
  float* out = (float*)d_out;
  char* ws = (char*)d_ws;

  const size_t MB = 1ull << 20;
  short* Tq  = (short*)(ws + 0 * MB);    // [1024,1024] bf16
  short* Tk  = (short*)(ws + 2 * MB);
  short* Tv  = (short*)(ws + 4 * MB);
  short* To  = (short*)(ws + 6 * MB);
  short* Xq  = (short*)(ws + 8 * MB);    // [16384,1024] bf16
  short* Xk  = (short*)(ws + 40 * MB);
  short* Xv  = (short*)(ws + 72 * MB);
  short* Qp  = (short*)(ws + 104 * MB);  // pre-scaled by log2e/32
  short* Kp  = (short*)(ws + 136 * MB);
  short* Vtb = (short*)(ws + 168 * MB);  // [1024,16384] bf16 (V^T) — total 200MB
  short* AO  = (short*)(ws + 8 * MB);    // reuse Xq slot (dead after Q-proj)

  const int n8 = CM * CD / 8;
  cvt_kernel<<<2048, 256, 0, stream>>>(query, Xq, n8);
  cvt_kernel<<<2048, 256, 0, stream>>>(key,   Xk, n8);
  cvt_kernel<<<2048, 256, 0, stream>>>(value, Xv, n8);
  wtrans_kernel<<<768, 256, 0, stream>>>(Wq, Wk, Wv, Tq, Tk, Tv);
  woconv_kernel<<<512, 256, 0, stream>>>(Wo, To);

  // q = X@Wq' scaled by d_model^-0.5 * log2(e)  (softmax runs in exp2 domain)
  gemm16_kernel<true><<<dim3(128, 8), 256, 0, stream>>>(Xq, Tq, Qp, CM, CD, CD, 0.03125f * 1.4426950408889634f);
  gemm16_kernel<true><<<dim3(128, 8), 256, 0, stream>>>(Xk, Tk, Kp, CM, CD, CD, 1.0f);
  // V^T = Tv @ Xv^T
  gemm16_kernel<true><<<dim3(8, 128), 256, 0, stream>>>(Tv, Xv, Vtb, CD, CM, CD, 1.0f);

  attn_kernel<<<dim3(16, 128), 256, 0, stream>>>(Qp, Kp, Vtb, AO);

  gemm16_kernel<false><<<dim3(128, 8), 256, 0, stream>>>(AO, To, out, CM, CD, CD, 1.0f);
}